// Round 10
// baseline (350.030 us; speedup 1.0000x reference)
//
#include <hip/hip_runtime.h>
#include <hip/hip_bf16.h>
#include <stdint.h>

typedef __attribute__((ext_vector_type(8))) short short8;
typedef __attribute__((ext_vector_type(4))) float floatx4;

#define DEVINL static __device__ __forceinline__

DEVINL float bfu(short v) {
  union { uint32_t i; float f; } x; x.i = ((uint32_t)(uint16_t)v) << 16; return x.f;
}
DEVINL uint16_t f2bf(float f) {
  union { float f; uint32_t i; } x; x.f = f;
  uint32_t i = x.i;
  i += 0x7fff + ((i >> 16) & 1);   // RNE
  return (uint16_t)(i >> 16);
}
DEVINL uint32_t cvtpk(float lo, float hi) {
  uint32_t r;
  asm("v_cvt_pk_bf16_f32 %0, %1, %2" : "=v"(r) : "v"(lo), "v"(hi));
  return r;
}

// ------------- fp32 [K][N] -> bf16 [N][K] transpose, LDS-tiled 64x64 -------------
__global__ __launch_bounds__(256)
void k_transpose_bf16(const float* __restrict__ in, uint16_t* __restrict__ out, int K, int N) {
  __shared__ float tile[64][65];
  const int tn = blockIdx.x * 64;
  const int tk = blockIdx.y * 64;
  const int tx = threadIdx.x & 63;
  const int ty = threadIdx.x >> 6;   // 0..3
#pragma unroll
  for (int i = 0; i < 64; i += 4)
    tile[ty + i][tx] = in[(long)(tk + ty + i) * N + tn + tx];
  __syncthreads();
#pragma unroll
  for (int i = 0; i < 64; i += 4)
    out[(long)(tn + ty + i) * K + tk + tx] = f2bf(tile[tx][ty + i]);
}

// ============ GEMM1: C = X(fp32) @ B^T (bf16), bf16 out. 256x256 tile ============
// R7-verified 2-barrier/K-tile schedule. R10: A-path fused fp32->bf16:
// per K-tile, after the 24 ds_reads (R7 order — R9 showed stage-before-reads
// collides with the read burst on the LDS pipe): issue B1(t1) gload_lds + 8
// dwordx4 fp32 A(t1) loads; gate vmcnt(2) [FIFO: B0(t1)2 | B1(t1)2 A(t1)8 |
// B0(t2)2 = 14, oldest 12 done], then cvt_pk + 4 linear ds_write_b128 into
// As[nbuf] (dest = gload_lds-equivalent addr; source col pre-swizzled),
// lgkm(0), barrier. Eliminates the standalone cvt kernel.
__global__ __launch_bounds__(512, 2)
void k_gemm1f(const float* __restrict__ X,     // [M][Kd] fp32
              const uint16_t* __restrict__ B,  // [N][Kd] bf16
              uint16_t* __restrict__ Cout,     // bf16 [M][N]
              int M, int N, int Kd, int tilesN)
{
  __shared__ uint16_t As[2][2][8192];  // [buf][half][128 rows x 64 cols]
  __shared__ uint16_t Bs[2][2][8192];

  const int nwg = gridDim.x;
  const int orig = blockIdx.x;
  const int q = nwg >> 3, r = nwg & 7;
  const int xcd = orig & 7, seq = orig >> 3;
  const int wgid = (xcd < r ? xcd * (q + 1) : r * (q + 1) + (xcd - r) * q) + seq;
  const int mt = wgid / tilesN;
  const int nt = wgid - mt * tilesN;

  const int t = threadIdx.x;
  const int l = t & 63;
  const int w = t >> 6;        // 0..7
  const int wm = w >> 2;       // A half (0..1)
  const int wn = w & 3;        // 0..3
  const long m0 = (long)mt * 256;
  const long n0 = (long)nt * 256;

  const int srow0 = t >> 3;                      // 0..63
  const int scol  = ((l & 7) ^ (l >> 3)) * 8;    // pre-swizzled col (elems)
  const int wbyte = w * 1024;

  const float* Xbase = X + m0 * Kd;
  const uint16_t* Bbase = B + n0 * Kd;

  const int fr = l & 15;
  const int kg = l >> 4;
  const int xorv = (l & 7) << 4;
  const int cb0 = (kg * 16) ^ xorv;
  const int cb1 = (64 + kg * 16) ^ xorv;

  floatx4 acc[8][4];
#pragma unroll
  for (int m = 0; m < 8; ++m)
#pragma unroll
    for (int n = 0; n < 4; ++n)
      acc[m][n] = (floatx4){0.f, 0.f, 0.f, 0.f};

  const int nK = Kd >> 6;   // 12 (even)

  auto stageB = [&](uint16_t* ldsHalf, const uint16_t* gHalf, int ktile) {
    const uint16_t* g0 = gHalf + (long)srow0 * Kd + ktile * 64 + scol;
    __builtin_amdgcn_global_load_lds(
        (const __attribute__((address_space(1))) void*)g0,
        (__attribute__((address_space(3))) void*)((char*)ldsHalf + wbyte), 16, 0, 0);
    __builtin_amdgcn_global_load_lds(
        (const __attribute__((address_space(1))) void*)(g0 + (long)64 * Kd),
        (__attribute__((address_space(3))) void*)((char*)ldsHalf + 8192 + wbyte), 16, 0, 0);
  };
  // A(t): 8 dwordx4 fp32 -> regs. Rows srow0 + {0,64,128,192}, 2 float4 each.
  auto loadA = [&](int ktile, float4* fa) {
    const float* g = Xbase + (long)srow0 * Kd + ktile * 64 + scol;
#pragma unroll
    for (int p = 0; p < 4; ++p) {
      fa[2 * p]     = *(const float4*)(g + (long)64 * p * Kd);
      fa[2 * p + 1] = *(const float4*)(g + (long)64 * p * Kd + 4);
    }
  };
  // cvt_pk + linear ds_write_b128 to the gload_lds-equivalent addresses.
  auto writeA = [&](int buf, const float4* fa) {
    char* base = (char*)&As[buf][0][0];
#pragma unroll
    for (int p = 0; p < 4; ++p) {   // p = row-group {0,64,128,192} = half p>>1, chunk p&1
      uint4 pk;
      pk.x = cvtpk(fa[2 * p].x, fa[2 * p].y);
      pk.y = cvtpk(fa[2 * p].z, fa[2 * p].w);
      pk.z = cvtpk(fa[2 * p + 1].x, fa[2 * p + 1].y);
      pk.w = cvtpk(fa[2 * p + 1].z, fa[2 * p + 1].w);
      *(uint4*)(base + (p >> 1) * 16384 + (p & 1) * 8192 + wbyte + l * 16) = pk;
    }
  };
  auto rdA = [&](int buf, int mm, int kk) -> short8 {
    const char* p = (const char*)&As[buf][wm][0] + mm * 2048 + fr * 128 + (kk ? cb1 : cb0);
    return *(const short8*)p;
  };
  auto rdB = [&](int buf, int nn, int kk) -> short8 {
    const char* p = (const char*)&Bs[buf][wn >> 1][0] + (wn & 1) * 8192 + nn * 2048 + fr * 128
                    + (kk ? cb1 : cb0);
    return *(const short8*)p;
  };

  // ---- prologue: B(0) full (4), A(0) regs (8), B0(1) (2); vmcnt(2) ----
  stageB(&Bs[0][0][0], Bbase, 0);
  stageB(&Bs[0][1][0], Bbase + (long)128 * Kd, 0);
  {
    float4 fa[8];
    loadA(0, fa);
    int t1 = 1 % nK;
    stageB(&Bs[t1 & 1][0][0], Bbase, t1);
    asm volatile("s_waitcnt vmcnt(2)" ::: "memory");
    writeA(0, fa);
    asm volatile("s_waitcnt lgkmcnt(0)" ::: "memory");
  }
  __builtin_amdgcn_s_barrier();

  short8 a[4][2], a2[4][2], bv0[2][2], bv1[2][2];

  for (int kt = 0; kt < nK; ++kt) {
    const int cbuf = kt & 1;
    const int nbuf = cbuf ^ 1;
    const int t1 = (kt + 1) % nK;
    const int t2 = (kt + 2) % nK;

    // 24 cbuf ds_reads FIRST (R7 order)
#pragma unroll
    for (int mm = 0; mm < 4; ++mm) { a[mm][0] = rdA(cbuf, mm, 0); a[mm][1] = rdA(cbuf, mm, 1); }
#pragma unroll
    for (int nn = 0; nn < 2; ++nn) { bv0[nn][0] = rdB(cbuf, nn, 0); bv0[nn][1] = rdB(cbuf, nn, 1); }
#pragma unroll
    for (int nn = 0; nn < 2; ++nn) { bv1[nn][0] = rdB(cbuf, 2 + nn, 0); bv1[nn][1] = rdB(cbuf, 2 + nn, 1); }
#pragma unroll
    for (int mm = 0; mm < 4; ++mm) { a2[mm][0] = rdA(cbuf, 4 + mm, 0); a2[mm][1] = rdA(cbuf, 4 + mm, 1); }

    // then: B1(t1) gload + A(t1) reg loads
    stageB(&Bs[nbuf][1][0], Bbase + (long)128 * Kd, t1);
    float4 fa[8];
    loadA(t1, fa);

    asm volatile("s_waitcnt lgkmcnt(8)" ::: "memory");
    __builtin_amdgcn_s_setprio(1);
#pragma unroll
    for (int mm = 0; mm < 4; ++mm)
#pragma unroll
      for (int nn = 0; nn < 2; ++nn) {
        acc[mm][nn] = __builtin_amdgcn_mfma_f32_16x16x32_bf16(a[mm][0], bv0[nn][0], acc[mm][nn], 0, 0, 0);
        acc[mm][nn] = __builtin_amdgcn_mfma_f32_16x16x32_bf16(a[mm][1], bv0[nn][1], acc[mm][nn], 0, 0, 0);
        acc[mm][2 + nn] = __builtin_amdgcn_mfma_f32_16x16x32_bf16(a[mm][0], bv1[nn][0], acc[mm][2 + nn], 0, 0, 0);
        acc[mm][2 + nn] = __builtin_amdgcn_mfma_f32_16x16x32_bf16(a[mm][1], bv1[nn][1], acc[mm][2 + nn], 0, 0, 0);
      }
    asm volatile("s_waitcnt lgkmcnt(0)" ::: "memory");
    __builtin_amdgcn_s_barrier();   // all waves done reading cbuf

    // mid stage: B0(t2) -> Bs[cbuf][0]; overlaps MFMA c2
    stageB(&Bs[cbuf][0][0], Bbase, t2);
#pragma unroll
    for (int mm = 0; mm < 4; ++mm)
#pragma unroll
      for (int nn = 0; nn < 2; ++nn) {
        acc[4 + mm][nn] = __builtin_amdgcn_mfma_f32_16x16x32_bf16(a2[mm][0], bv0[nn][0], acc[4 + mm][nn], 0, 0, 0);
        acc[4 + mm][nn] = __builtin_amdgcn_mfma_f32_16x16x32_bf16(a2[mm][1], bv0[nn][1], acc[4 + mm][nn], 0, 0, 0);
        acc[4 + mm][2 + nn] = __builtin_amdgcn_mfma_f32_16x16x32_bf16(a2[mm][0], bv1[nn][0], acc[4 + mm][2 + nn], 0, 0, 0);
        acc[4 + mm][2 + nn] = __builtin_amdgcn_mfma_f32_16x16x32_bf16(a2[mm][1], bv1[nn][1], acc[4 + mm][2 + nn], 0, 0, 0);
      }
    __builtin_amdgcn_s_setprio(0);

    // gate: oldest 12 = B0(t1),B1(t1),A(t1) done; B0(t2) stays in flight
    asm volatile("s_waitcnt vmcnt(2)" ::: "memory");
    writeA(nbuf, fa);
    asm volatile("s_waitcnt lgkmcnt(0)" ::: "memory");
    __builtin_amdgcn_s_barrier();
  }

  // drain wrapped tail stages (they write Bs)
  asm volatile("s_waitcnt vmcnt(0)" ::: "memory");
  __builtin_amdgcn_s_barrier();

  // LDS-staged coalesced bf16 epilogue (C/D: col=lane&15, row=(lane>>4)*4+reg)
  const int orow = (l >> 4) * 4;
  const int ocol = l & 15;
  {
    char* eb = (char*)&As[0][0][0] + (size_t)w * 4096;   // wave-private 4KB
    const int rr0 = l >> 3;
    const int cc0 = (l & 7) * 8;
#pragma unroll
    for (int mm = 0; mm < 8; ++mm) {
#pragma unroll
      for (int nn = 0; nn < 4; ++nn)
#pragma unroll
        for (int r2 = 0; r2 < 4; ++r2) {
          int rrow = orow + r2;
          int byo = ((rrow * 64 + nn * 16 + ocol) * 2) ^ ((rrow & 7) << 4);
          *(uint16_t*)(eb + byo) = f2bf(acc[mm][nn][r2]);
        }
#pragma unroll
      for (int p = 0; p < 2; ++p) {
        int rrow = rr0 + p * 8;
        int byo = ((rrow * 64 + cc0) * 2) ^ ((rrow & 7) << 4);
        short8 vvv = *(const short8*)(eb + byo);
        *(short8*)(&Cout[(m0 + wm * 128 + mm * 16 + rrow) * N + n0 + wn * 64 + cc0]) = vvv;
      }
    }
  }
}

// ============ 256x256 bf16 GEMM (R7 EXACT), C = A @ B^T ============
template<int OUT_BF16>
__global__ __launch_bounds__(512, 2)
void k_gemm256(const uint16_t* __restrict__ A,   // [M][Kd] bf16
               const uint16_t* __restrict__ B,   // [N][Kd] bf16
               void* __restrict__ Cout,          // bf16 [M][N] or fp32 [M][N]
               const float* __restrict__ bias,   // nullable (fp32 path)
               int M, int N, int Kd, int tilesN)
{
  __shared__ uint16_t As[2][2][8192];
  __shared__ uint16_t Bs[2][2][8192];

  const int nwg = gridDim.x;
  const int orig = blockIdx.x;
  const int q = nwg >> 3, r = nwg & 7;
  const int xcd = orig & 7, seq = orig >> 3;
  const int wgid = (xcd < r ? xcd * (q + 1) : r * (q + 1) + (xcd - r) * q) + seq;
  const int mt = wgid / tilesN;
  const int nt = wgid - mt * tilesN;

  const int t = threadIdx.x;
  const int l = t & 63;
  const int w = t >> 6;
  const int wm = w >> 2;
  const int wn = w & 3;
  const long m0 = (long)mt * 256;
  const long n0 = (long)nt * 256;

  const int srow0 = t >> 3;
  const int scol  = ((l & 7) ^ (l >> 3)) * 8;
  const int wbyte = w * 1024;

  const uint16_t* Abase = A + m0 * Kd;
  const uint16_t* Bbase = B + n0 * Kd;

  const int fr = l & 15;
  const int kg = l >> 4;
  const int xorv = (l & 7) << 4;
  const int cb0 = (kg * 16) ^ xorv;
  const int cb1 = (64 + kg * 16) ^ xorv;

  floatx4 acc[8][4];
#pragma unroll
  for (int m = 0; m < 8; ++m)
#pragma unroll
    for (int n = 0; n < 4; ++n)
      acc[m][n] = (floatx4){0.f, 0.f, 0.f, 0.f};

  const int nK = Kd >> 6;

  auto stage = [&](uint16_t* ldsHalf, const uint16_t* gHalf, int ktile) {
    const uint16_t* g0 = gHalf + (long)srow0 * Kd + ktile * 64 + scol;
    __builtin_amdgcn_global_load_lds(
        (const __attribute__((address_space(1))) void*)g0,
        (__attribute__((address_space(3))) void*)((char*)ldsHalf + wbyte), 16, 0, 0);
    __builtin_amdgcn_global_load_lds(
        (const __attribute__((address_space(1))) void*)(g0 + (long)64 * Kd),
        (__attribute__((address_space(3))) void*)((char*)ldsHalf + 8192 + wbyte), 16, 0, 0);
  };
  auto rdA = [&](int buf, int mm, int kk) -> short8 {
    const char* p = (const char*)&As[buf][wm][0] + mm * 2048 + fr * 128 + (kk ? cb1 : cb0);
    return *(const short8*)p;
  };
  auto rdB = [&](int buf, int nn, int kk) -> short8 {
    const char* p = (const char*)&Bs[buf][wn >> 1][0] + (wn & 1) * 8192 + nn * 2048 + fr * 128
                    + (kk ? cb1 : cb0);
    return *(const short8*)p;
  };

  stage(&Bs[0][0][0], Bbase, 0);
  stage(&Bs[0][1][0], Bbase + (long)128 * Kd, 0);
  stage(&As[0][0][0], Abase, 0);
  stage(&As[0][1][0], Abase + (long)128 * Kd, 0);
  {
    int t1 = 1 % nK;
    stage(&Bs[t1 & 1][0][0], Bbase, t1);
    stage(&As[t1 & 1][0][0], Abase, t1);
  }
  asm volatile("s_waitcnt vmcnt(4)" ::: "memory");
  __builtin_amdgcn_s_barrier();

  short8 a[4][2], a2[4][2], bv0[2][2], bv1[2][2];

  for (int kt = 0; kt < nK; ++kt) {
    const int cbuf = kt & 1;
    const int nbuf = cbuf ^ 1;
    const int t1 = (kt + 1) % nK;
    const int t2 = (kt + 2) % nK;

#pragma unroll
    for (int mm = 0; mm < 4; ++mm) { a[mm][0] = rdA(cbuf, mm, 0); a[mm][1] = rdA(cbuf, mm, 1); }
#pragma unroll
    for (int nn = 0; nn < 2; ++nn) { bv0[nn][0] = rdB(cbuf, nn, 0); bv0[nn][1] = rdB(cbuf, nn, 1); }
#pragma unroll
    for (int nn = 0; nn < 2; ++nn) { bv1[nn][0] = rdB(cbuf, 2 + nn, 0); bv1[nn][1] = rdB(cbuf, 2 + nn, 1); }
#pragma unroll
    for (int mm = 0; mm < 4; ++mm) { a2[mm][0] = rdA(cbuf, 4 + mm, 0); a2[mm][1] = rdA(cbuf, 4 + mm, 1); }

    stage(&Bs[nbuf][1][0], Bbase + (long)128 * Kd, t1);
    stage(&As[nbuf][1][0], Abase + (long)128 * Kd, t1);

    asm volatile("s_waitcnt lgkmcnt(8)" ::: "memory");
    __builtin_amdgcn_s_setprio(1);
#pragma unroll
    for (int mm = 0; mm < 4; ++mm)
#pragma unroll
      for (int nn = 0; nn < 2; ++nn) {
        acc[mm][nn] = __builtin_amdgcn_mfma_f32_16x16x32_bf16(a[mm][0], bv0[nn][0], acc[mm][nn], 0, 0, 0);
        acc[mm][nn] = __builtin_amdgcn_mfma_f32_16x16x32_bf16(a[mm][1], bv0[nn][1], acc[mm][nn], 0, 0, 0);
        acc[mm][2 + nn] = __builtin_amdgcn_mfma_f32_16x16x32_bf16(a[mm][0], bv1[nn][0], acc[mm][2 + nn], 0, 0, 0);
        acc[mm][2 + nn] = __builtin_amdgcn_mfma_f32_16x16x32_bf16(a[mm][1], bv1[nn][1], acc[mm][2 + nn], 0, 0, 0);
      }
    asm volatile("s_waitcnt lgkmcnt(0)" ::: "memory");
    __builtin_amdgcn_s_barrier();

    stage(&Bs[cbuf][0][0], Bbase, t2);
    stage(&As[cbuf][0][0], Abase, t2);
#pragma unroll
    for (int mm = 0; mm < 4; ++mm)
#pragma unroll
      for (int nn = 0; nn < 2; ++nn) {
        acc[4 + mm][nn] = __builtin_amdgcn_mfma_f32_16x16x32_bf16(a2[mm][0], bv0[nn][0], acc[4 + mm][nn], 0, 0, 0);
        acc[4 + mm][nn] = __builtin_amdgcn_mfma_f32_16x16x32_bf16(a2[mm][1], bv0[nn][1], acc[4 + mm][nn], 0, 0, 0);
        acc[4 + mm][2 + nn] = __builtin_amdgcn_mfma_f32_16x16x32_bf16(a2[mm][0], bv1[nn][0], acc[4 + mm][2 + nn], 0, 0, 0);
        acc[4 + mm][2 + nn] = __builtin_amdgcn_mfma_f32_16x16x32_bf16(a2[mm][1], bv1[nn][1], acc[4 + mm][2 + nn], 0, 0, 0);
      }
    __builtin_amdgcn_s_setprio(0);

    asm volatile("s_waitcnt vmcnt(4)" ::: "memory");
    __builtin_amdgcn_s_barrier();
  }

  asm volatile("s_waitcnt vmcnt(0)" ::: "memory");
  __builtin_amdgcn_s_barrier();

  const int orow = (l >> 4) * 4;
  const int ocol = l & 15;
  if (OUT_BF16) {
    uint16_t* C = (uint16_t*)Cout;
    char* eb = (char*)&As[0][0][0] + (size_t)w * 4096;
    const int rr0 = l >> 3;
    const int cc0 = (l & 7) * 8;
#pragma unroll
    for (int mm = 0; mm < 8; ++mm) {
#pragma unroll
      for (int nn = 0; nn < 4; ++nn)
#pragma unroll
        for (int r2 = 0; r2 < 4; ++r2) {
          int rrow = orow + r2;
          int byo = ((rrow * 64 + nn * 16 + ocol) * 2) ^ ((rrow & 7) << 4);
          *(uint16_t*)(eb + byo) = f2bf(acc[mm][nn][r2]);
        }
#pragma unroll
      for (int p = 0; p < 2; ++p) {
        int rrow = rr0 + p * 8;
        int byo = ((rrow * 64 + cc0) * 2) ^ ((rrow & 7) << 4);
        short8 vvv = *(const short8*)(eb + byo);
        *(short8*)(&C[(m0 + wm * 128 + mm * 16 + rrow) * N + n0 + wn * 64 + cc0]) = vvv;
      }
    }
  } else {
    float* C = (float*)Cout;
    float* eb = (float*)&As[0][0][0] + (size_t)w * 1024;
    const int rr0 = l >> 4;
    const int cc0 = (l & 15) * 4;
    float4 bias4 = make_float4(0.f, 0.f, 0.f, 0.f);
    if (bias) bias4 = *(const float4*)(bias + n0 + wn * 64 + cc0);
#pragma unroll
    for (int mm = 0; mm < 8; ++mm) {
#pragma unroll
      for (int nn = 0; nn < 4; ++nn)
#pragma unroll
        for (int r2 = 0; r2 < 4; ++r2)
          eb[(orow + r2) * 64 + nn * 16 + ocol] = acc[mm][nn][r2];
#pragma unroll
      for (int p = 0; p < 4; ++p) {
        int rrow = rr0 + p * 4;
        float4 vvv = *(const float4*)(eb + rrow * 64 + cc0);
        vvv.x += bias4.x; vvv.y += bias4.y; vvv.z += bias4.z; vvv.w += bias4.w;
        *(float4*)(&C[(m0 + wm * 128 + mm * 16 + rrow) * N + n0 + wn * 64 + cc0]) = vvv;
      }
    }
  }
}

// ---------------- per-token 6-head attention, 16 lanes per token ----------------
__global__ __launch_bounds__(256)
void k_attn(const uint16_t* __restrict__ qkv, uint16_t* __restrict__ outp) {
  const int wid = blockIdx.x * 4 + (threadIdx.x >> 6);
  const int l = threadIdx.x & 63;
  const int sub = l >> 4;
  const int i = l & 15;
  const int token = wid * 4 + sub;
  const uint16_t* row = qkv + (long)token * 2304 + i * 8;

  short8 kv[6];
  float qf[6][8];
#pragma unroll
  for (int h = 0; h < 6; ++h) {
    short8 qv = *(const short8*)(row + h * 128);
    kv[h] = *(const short8*)(row + 768 + h * 128);
#pragma unroll
    for (int e = 0; e < 8; ++e) qf[h][e] = bfu(qv[e]);
  }

  float s[36];
#pragma unroll
  for (int g = 0; g < 6; ++g) {
    float kf[8];
#pragma unroll
    for (int e = 0; e < 8; ++e) kf[e] = bfu(kv[g][e]);
#pragma unroll
    for (int h = 0; h < 6; ++h) {
      float a = 0.f;
#pragma unroll
      for (int e = 0; e < 8; ++e) a += qf[h][e] * kf[e];
      s[h * 6 + g] = a;
    }
  }

#pragma unroll
  for (int off = 8; off > 0; off >>= 1)
#pragma unroll
    for (int j = 0; j < 36; ++j)
      s[j] += __shfl_xor(s[j], off, 64);

  const float scale = 0.088388347648318447f;  // 128^-0.5
  float p[36];
#pragma unroll
  for (int h = 0; h < 6; ++h) {
    float mx = s[h * 6];
#pragma unroll
    for (int g = 1; g < 6; ++g) mx = fmaxf(mx, s[h * 6 + g]);
    float sum = 0.f;
#pragma unroll
    for (int g = 0; g < 6; ++g) {
      float e = __expf((s[h * 6 + g] - mx) * scale);
      p[h * 6 + g] = e; sum += e;
    }
    float inv = 1.f / sum;
#pragma unroll
    for (int g = 0; g < 6; ++g) p[h * 6 + g] *= inv;
  }

  float o[6][8];
#pragma unroll
  for (int h = 0; h < 6; ++h)
#pragma unroll
    for (int e = 0; e < 8; ++e) o[h][e] = 0.f;
#pragma unroll
  for (int g = 0; g < 6; ++g) {
    short8 vv = *(const short8*)(row + 1536 + g * 128);
    float vf[8];
#pragma unroll
    for (int e = 0; e < 8; ++e) vf[e] = bfu(vv[e]);
#pragma unroll
    for (int h = 0; h < 6; ++h)
#pragma unroll
      for (int e = 0; e < 8; ++e) o[h][e] += p[h * 6 + g] * vf[e];
  }

  const int b = token >> 12, nn = token & 4095;
#pragma unroll
  for (int h = 0; h < 6; ++h) {
    short8 ov;
#pragma unroll
    for (int e = 0; e < 8; ++e) ov[e] = (short)f2bf(o[h][e]);
    *(short8*)(outp + ((long)(b * 6 + h) * 4096 + nn) * 128 + i * 8) = ov;
  }
}

extern "C" void kernel_launch(void* const* d_in, const int* in_sizes, int n_in,
                              void* d_out, int out_size, void* d_ws, size_t ws_size,
                              hipStream_t stream) {
  const float* x      = (const float*)d_in[0];
  const float* w_qkv  = (const float*)d_in[1];
  const float* w_proj = (const float*)d_in[2];
  const float* b_proj = (const float*)d_in[3];
  float* out = (float*)d_out;

  const int Cc = 768, C3 = 2304;
  const int Mtok = in_sizes[0] / Cc;  // 32768

  char* ws = (char*)d_ws;
  uint16_t* att_bf = (uint16_t*)ws;                            // 50,331,648 B region
  uint16_t* qkv_bf = (uint16_t*)(ws + 50331648);               // 150,994,944 B
  uint16_t* wqkvT  = (uint16_t*)(ws + 50331648 + 150994944);   // 3,538,944 B
  uint16_t* wprojT = (uint16_t*)(ws + 50331648 + 150994944 + 3538944); // 1,179,648 B

  hipLaunchKernelGGL(k_transpose_bf16, dim3(C3 / 64, Cc / 64), dim3(256), 0, stream,
                     w_qkv, wqkvT, Cc, C3);
  hipLaunchKernelGGL(k_transpose_bf16, dim3(Cc / 64, Cc / 64), dim3(256), 0, stream,
                     w_proj, wprojT, Cc, Cc);

  hipLaunchKernelGGL(k_gemm1f, dim3((Mtok / 256) * (C3 / 256)), dim3(512), 0, stream,
                     x, wqkvT, qkv_bf, Mtok, C3, Cc, C3 / 256);

  hipLaunchKernelGGL(k_attn, dim3(Mtok / 16), dim3(256), 0, stream, qkv_bf, att_bf);

  hipLaunchKernelGGL((k_gemm256<0>), dim3((Mtok / 256) * (Cc / 256)), dim3(512), 0, stream,
                     att_bf, wprojT, (void*)out, b_proj, Mtok, Cc, Cc, Cc / 256);
}

// Round 11
// 246.185 us; speedup vs baseline: 1.4218x; 1.4218x over previous
//
#include <hip/hip_runtime.h>
#include <hip/hip_bf16.h>
#include <stdint.h>

typedef __attribute__((ext_vector_type(8))) short short8;
typedef __attribute__((ext_vector_type(4))) float floatx4;

#define DEVINL static __device__ __forceinline__

DEVINL float bfu(short v) {
  union { uint32_t i; float f; } x; x.i = ((uint32_t)(uint16_t)v) << 16; return x.f;
}
DEVINL uint16_t f2bf(float f) {
  union { float f; uint32_t i; } x; x.f = f;
  uint32_t i = x.i;
  i += 0x7fff + ((i >> 16) & 1);   // RNE
  return (uint16_t)(i >> 16);
}

// ============ fused prep: fp32->bf16 cvt of x + both weight transposes ============
// Pure data-parallel; blocks partitioned by blockIdx. No cross-block deps.
DEVINL void transpose_tile(const float* in, uint16_t* out, int K, int N,
                           int bx, int by, float (*tile)[65]) {
  const int tn = bx * 64;
  const int tk = by * 64;
  const int tx = threadIdx.x & 63;
  const int ty = threadIdx.x >> 6;   // 0..3
#pragma unroll
  for (int i = 0; i < 64; i += 4)
    tile[ty + i][tx] = in[(long)(tk + ty + i) * N + tn + tx];
  __syncthreads();
#pragma unroll
  for (int i = 0; i < 64; i += 4)
    out[(long)(tn + ty + i) * K + tk + tx] = f2bf(tile[tx][ty + i]);
}

__global__ __launch_bounds__(256)
void k_prep(const float* __restrict__ x, uint16_t* __restrict__ x_bf, int n4,
            const float* __restrict__ w_qkv, uint16_t* __restrict__ wqkvT,
            const float* __restrict__ w_proj, uint16_t* __restrict__ wprojT) {
  __shared__ float tile[64][65];
  const int bid = blockIdx.x;
  if (bid < 2048) {
    // x fp32 -> bf16, grid-stride over 2048 blocks
    int i = bid * 256 + threadIdx.x;
    const int stride = 2048 * 256;
    for (; i < n4; i += stride) {
      float4 v = ((const float4*)x)[i];
      ushort4 o;
      o.x = f2bf(v.x); o.y = f2bf(v.y); o.z = f2bf(v.z); o.w = f2bf(v.w);
      ((ushort4*)x_bf)[i] = o;
    }
  } else if (bid < 2048 + 36 * 12) {
    // w_qkv [768][2304] -> wqkvT [2304][768]
    const int tq = bid - 2048;
    transpose_tile(w_qkv, wqkvT, 768, 2304, tq % 36, tq / 36, tile);
  } else {
    // w_proj [768][768] -> wprojT [768][768]
    const int tp = bid - (2048 + 36 * 12);
    transpose_tile(w_proj, wprojT, 768, 768, tp % 12, tp / 12, tile);
  }
}

// ============ 256x256 bf16 GEMM (R7 EXACT), C = A @ B^T (B stored [N][K]) ============
// 2 barriers/K-tile, 2-deep counted-vmcnt(4) ledger:
//   24 ds_reads (cbuf) ; stage B1,A1(t1)->nbuf ; lgkm(8) ; MFMA c1 (32) ;
//   lgkm(0) ; BAR ; stage B0,A0(t2)->cbuf ; MFMA c2 (32) ; vmcnt(4) ; BAR.
// T2 swizzle (row&7)<<4 both-sides; T5 setprio; XCD-bijective remap (m204).
template<int OUT_BF16>
__global__ __launch_bounds__(512, 2)
void k_gemm256(const uint16_t* __restrict__ A,   // [M][Kd] bf16
               const uint16_t* __restrict__ B,   // [N][Kd] bf16
               void* __restrict__ Cout,          // bf16 [M][N] or fp32 [M][N]
               const float* __restrict__ bias,   // nullable (fp32 path)
               int M, int N, int Kd, int tilesN)
{
  __shared__ uint16_t As[2][2][8192];
  __shared__ uint16_t Bs[2][2][8192];

  const int nwg = gridDim.x;
  const int orig = blockIdx.x;
  const int q = nwg >> 3, r = nwg & 7;
  const int xcd = orig & 7, seq = orig >> 3;
  const int wgid = (xcd < r ? xcd * (q + 1) : r * (q + 1) + (xcd - r) * q) + seq;
  const int mt = wgid / tilesN;
  const int nt = wgid - mt * tilesN;

  const int t = threadIdx.x;
  const int l = t & 63;
  const int w = t >> 6;
  const int wm = w >> 2;
  const int wn = w & 3;
  const long m0 = (long)mt * 256;
  const long n0 = (long)nt * 256;

  const int srow0 = t >> 3;
  const int scol  = ((l & 7) ^ (l >> 3)) * 8;
  const int wbyte = w * 1024;

  const uint16_t* Abase = A + m0 * Kd;
  const uint16_t* Bbase = B + n0 * Kd;

  const int fr = l & 15;
  const int kg = l >> 4;
  const int xorv = (l & 7) << 4;
  const int cb0 = (kg * 16) ^ xorv;
  const int cb1 = (64 + kg * 16) ^ xorv;

  floatx4 acc[8][4];
#pragma unroll
  for (int m = 0; m < 8; ++m)
#pragma unroll
    for (int n = 0; n < 4; ++n)
      acc[m][n] = (floatx4){0.f, 0.f, 0.f, 0.f};

  const int nK = Kd >> 6;

  auto stage = [&](uint16_t* ldsHalf, const uint16_t* gHalf, int ktile) {
    const uint16_t* g0 = gHalf + (long)srow0 * Kd + ktile * 64 + scol;
    __builtin_amdgcn_global_load_lds(
        (const __attribute__((address_space(1))) void*)g0,
        (__attribute__((address_space(3))) void*)((char*)ldsHalf + wbyte), 16, 0, 0);
    __builtin_amdgcn_global_load_lds(
        (const __attribute__((address_space(1))) void*)(g0 + (long)64 * Kd),
        (__attribute__((address_space(3))) void*)((char*)ldsHalf + 8192 + wbyte), 16, 0, 0);
  };
  auto rdA = [&](int buf, int mm, int kk) -> short8 {
    const char* p = (const char*)&As[buf][wm][0] + mm * 2048 + fr * 128 + (kk ? cb1 : cb0);
    return *(const short8*)p;
  };
  auto rdB = [&](int buf, int nn, int kk) -> short8 {
    const char* p = (const char*)&Bs[buf][wn >> 1][0] + (wn & 1) * 8192 + nn * 2048 + fr * 128
                    + (kk ? cb1 : cb0);
    return *(const short8*)p;
  };

  stage(&Bs[0][0][0], Bbase, 0);
  stage(&Bs[0][1][0], Bbase + (long)128 * Kd, 0);
  stage(&As[0][0][0], Abase, 0);
  stage(&As[0][1][0], Abase + (long)128 * Kd, 0);
  {
    int t1 = 1 % nK;
    stage(&Bs[t1 & 1][0][0], Bbase, t1);
    stage(&As[t1 & 1][0][0], Abase, t1);
  }
  asm volatile("s_waitcnt vmcnt(4)" ::: "memory");
  __builtin_amdgcn_s_barrier();

  short8 a[4][2], a2[4][2], bv0[2][2], bv1[2][2];

  for (int kt = 0; kt < nK; ++kt) {
    const int cbuf = kt & 1;
    const int nbuf = cbuf ^ 1;
    const int t1 = (kt + 1) % nK;
    const int t2 = (kt + 2) % nK;

    // 24 cbuf ds_reads first (R7 order — hoisting stages regressed, R9)
#pragma unroll
    for (int mm = 0; mm < 4; ++mm) { a[mm][0] = rdA(cbuf, mm, 0); a[mm][1] = rdA(cbuf, mm, 1); }
#pragma unroll
    for (int nn = 0; nn < 2; ++nn) { bv0[nn][0] = rdB(cbuf, nn, 0); bv0[nn][1] = rdB(cbuf, nn, 1); }
#pragma unroll
    for (int nn = 0; nn < 2; ++nn) { bv1[nn][0] = rdB(cbuf, 2 + nn, 0); bv1[nn][1] = rdB(cbuf, 2 + nn, 1); }
#pragma unroll
    for (int mm = 0; mm < 4; ++mm) { a2[mm][0] = rdA(cbuf, 4 + mm, 0); a2[mm][1] = rdA(cbuf, 4 + mm, 1); }

    stage(&Bs[nbuf][1][0], Bbase + (long)128 * Kd, t1);
    stage(&As[nbuf][1][0], Abase + (long)128 * Kd, t1);

    asm volatile("s_waitcnt lgkmcnt(8)" ::: "memory");
    __builtin_amdgcn_s_setprio(1);
#pragma unroll
    for (int mm = 0; mm < 4; ++mm)
#pragma unroll
      for (int nn = 0; nn < 2; ++nn) {
        acc[mm][nn] = __builtin_amdgcn_mfma_f32_16x16x32_bf16(a[mm][0], bv0[nn][0], acc[mm][nn], 0, 0, 0);
        acc[mm][nn] = __builtin_amdgcn_mfma_f32_16x16x32_bf16(a[mm][1], bv0[nn][1], acc[mm][nn], 0, 0, 0);
        acc[mm][2 + nn] = __builtin_amdgcn_mfma_f32_16x16x32_bf16(a[mm][0], bv1[nn][0], acc[mm][2 + nn], 0, 0, 0);
        acc[mm][2 + nn] = __builtin_amdgcn_mfma_f32_16x16x32_bf16(a[mm][1], bv1[nn][1], acc[mm][2 + nn], 0, 0, 0);
      }
    asm volatile("s_waitcnt lgkmcnt(0)" ::: "memory");
    __builtin_amdgcn_s_barrier();

    stage(&Bs[cbuf][0][0], Bbase, t2);
    stage(&As[cbuf][0][0], Abase, t2);
#pragma unroll
    for (int mm = 0; mm < 4; ++mm)
#pragma unroll
      for (int nn = 0; nn < 2; ++nn) {
        acc[4 + mm][nn] = __builtin_amdgcn_mfma_f32_16x16x32_bf16(a2[mm][0], bv0[nn][0], acc[4 + mm][nn], 0, 0, 0);
        acc[4 + mm][nn] = __builtin_amdgcn_mfma_f32_16x16x32_bf16(a2[mm][1], bv0[nn][1], acc[4 + mm][nn], 0, 0, 0);
        acc[4 + mm][2 + nn] = __builtin_amdgcn_mfma_f32_16x16x32_bf16(a2[mm][0], bv1[nn][0], acc[4 + mm][2 + nn], 0, 0, 0);
        acc[4 + mm][2 + nn] = __builtin_amdgcn_mfma_f32_16x16x32_bf16(a2[mm][1], bv1[nn][1], acc[4 + mm][2 + nn], 0, 0, 0);
      }
    __builtin_amdgcn_s_setprio(0);

    asm volatile("s_waitcnt vmcnt(4)" ::: "memory");
    __builtin_amdgcn_s_barrier();
  }

  asm volatile("s_waitcnt vmcnt(0)" ::: "memory");
  __builtin_amdgcn_s_barrier();

  const int orow = (l >> 4) * 4;
  const int ocol = l & 15;
  if (OUT_BF16) {
    uint16_t* C = (uint16_t*)Cout;
    char* eb = (char*)&As[0][0][0] + (size_t)w * 4096;
    const int rr0 = l >> 3;
    const int cc0 = (l & 7) * 8;
#pragma unroll
    for (int mm = 0; mm < 8; ++mm) {
#pragma unroll
      for (int nn = 0; nn < 4; ++nn)
#pragma unroll
        for (int r2 = 0; r2 < 4; ++r2) {
          int rrow = orow + r2;
          int byo = ((rrow * 64 + nn * 16 + ocol) * 2) ^ ((rrow & 7) << 4);
          *(uint16_t*)(eb + byo) = f2bf(acc[mm][nn][r2]);
        }
#pragma unroll
      for (int p = 0; p < 2; ++p) {
        int rrow = rr0 + p * 8;
        int byo = ((rrow * 64 + cc0) * 2) ^ ((rrow & 7) << 4);
        short8 vvv = *(const short8*)(eb + byo);
        *(short8*)(&C[(m0 + wm * 128 + mm * 16 + rrow) * N + n0 + wn * 64 + cc0]) = vvv;
      }
    }
  } else {
    float* C = (float*)Cout;
    float* eb = (float*)&As[0][0][0] + (size_t)w * 1024;
    const int rr0 = l >> 4;
    const int cc0 = (l & 15) * 4;
    float4 bias4 = make_float4(0.f, 0.f, 0.f, 0.f);
    if (bias) bias4 = *(const float4*)(bias + n0 + wn * 64 + cc0);
#pragma unroll
    for (int mm = 0; mm < 8; ++mm) {
#pragma unroll
      for (int nn = 0; nn < 4; ++nn)
#pragma unroll
        for (int r2 = 0; r2 < 4; ++r2)
          eb[(orow + r2) * 64 + nn * 16 + ocol] = acc[mm][nn][r2];
#pragma unroll
      for (int p = 0; p < 4; ++p) {
        int rrow = rr0 + p * 4;
        float4 vvv = *(const float4*)(eb + rrow * 64 + cc0);
        vvv.x += bias4.x; vvv.y += bias4.y; vvv.z += bias4.z; vvv.w += bias4.w;
        *(float4*)(&C[(m0 + wm * 128 + mm * 16 + rrow) * N + n0 + wn * 64 + cc0]) = vvv;
      }
    }
  }
}

// ---------------- per-token 6-head attention, 16 lanes per token ----------------
__global__ __launch_bounds__(256)
void k_attn(const uint16_t* __restrict__ qkv, uint16_t* __restrict__ outp) {
  const int wid = blockIdx.x * 4 + (threadIdx.x >> 6);
  const int l = threadIdx.x & 63;
  const int sub = l >> 4;
  const int i = l & 15;
  const int token = wid * 4 + sub;
  const uint16_t* row = qkv + (long)token * 2304 + i * 8;

  short8 kv[6];
  float qf[6][8];
#pragma unroll
  for (int h = 0; h < 6; ++h) {
    short8 qv = *(const short8*)(row + h * 128);
    kv[h] = *(const short8*)(row + 768 + h * 128);
#pragma unroll
    for (int e = 0; e < 8; ++e) qf[h][e] = bfu(qv[e]);
  }

  float s[36];
#pragma unroll
  for (int g = 0; g < 6; ++g) {
    float kf[8];
#pragma unroll
    for (int e = 0; e < 8; ++e) kf[e] = bfu(kv[g][e]);
#pragma unroll
    for (int h = 0; h < 6; ++h) {
      float a = 0.f;
#pragma unroll
      for (int e = 0; e < 8; ++e) a += qf[h][e] * kf[e];
      s[h * 6 + g] = a;
    }
  }

#pragma unroll
  for (int off = 8; off > 0; off >>= 1)
#pragma unroll
    for (int j = 0; j < 36; ++j)
      s[j] += __shfl_xor(s[j], off, 64);

  const float scale = 0.088388347648318447f;  // 128^-0.5
  float p[36];
#pragma unroll
  for (int h = 0; h < 6; ++h) {
    float mx = s[h * 6];
#pragma unroll
    for (int g = 1; g < 6; ++g) mx = fmaxf(mx, s[h * 6 + g]);
    float sum = 0.f;
#pragma unroll
    for (int g = 0; g < 6; ++g) {
      float e = __expf((s[h * 6 + g] - mx) * scale);
      p[h * 6 + g] = e; sum += e;
    }
    float inv = 1.f / sum;
#pragma unroll
    for (int g = 0; g < 6; ++g) p[h * 6 + g] *= inv;
  }

  float o[6][8];
#pragma unroll
  for (int h = 0; h < 6; ++h)
#pragma unroll
    for (int e = 0; e < 8; ++e) o[h][e] = 0.f;
#pragma unroll
  for (int g = 0; g < 6; ++g) {
    short8 vv = *(const short8*)(row + 1536 + g * 128);
    float vf[8];
#pragma unroll
    for (int e = 0; e < 8; ++e) vf[e] = bfu(vv[e]);
#pragma unroll
    for (int h = 0; h < 6; ++h)
#pragma unroll
      for (int e = 0; e < 8; ++e) o[h][e] += p[h * 6 + g] * vf[e];
  }

  const int b = token >> 12, nn = token & 4095;
#pragma unroll
  for (int h = 0; h < 6; ++h) {
    short8 ov;
#pragma unroll
    for (int e = 0; e < 8; ++e) ov[e] = (short)f2bf(o[h][e]);
    *(short8*)(outp + ((long)(b * 6 + h) * 4096 + nn) * 128 + i * 8) = ov;
  }
}

extern "C" void kernel_launch(void* const* d_in, const int* in_sizes, int n_in,
                              void* d_out, int out_size, void* d_ws, size_t ws_size,
                              hipStream_t stream) {
  const float* x      = (const float*)d_in[0];
  const float* w_qkv  = (const float*)d_in[1];
  const float* w_proj = (const float*)d_in[2];
  const float* b_proj = (const float*)d_in[3];
  float* out = (float*)d_out;

  const int Cc = 768, C3 = 2304;
  const int Mtok = in_sizes[0] / Cc;  // 32768

  char* ws = (char*)d_ws;
  uint16_t* x_bf   = (uint16_t*)ws;                            // 50,331,648 B
  uint16_t* att_bf = x_bf;                                     // reuse (x_bf dead after GEMM1)
  uint16_t* qkv_bf = (uint16_t*)(ws + 50331648);               // 150,994,944 B
  uint16_t* wqkvT  = (uint16_t*)(ws + 50331648 + 150994944);   // 3,538,944 B
  uint16_t* wprojT = (uint16_t*)(ws + 50331648 + 150994944 + 3538944); // 1,179,648 B

  // fused prep: cvt (2048 blocks) + w_qkv transpose (432) + w_proj transpose (144)
  hipLaunchKernelGGL(k_prep, dim3(2048 + 432 + 144), dim3(256), 0, stream,
                     x, x_bf, Mtok * Cc / 4, w_qkv, wqkvT, w_proj, wprojT);

  hipLaunchKernelGGL((k_gemm256<1>), dim3((Mtok / 256) * (C3 / 256)), dim3(512), 0, stream,
                     x_bf, wqkvT, (void*)qkv_bf, (const float*)nullptr, Mtok, C3, Cc, C3 / 256);

  hipLaunchKernelGGL(k_attn, dim3(Mtok / 16), dim3(256), 0, stream, qkv_bf, att_bf);

  hipLaunchKernelGGL((k_gemm256<0>), dim3((Mtok / 256) * (Cc / 256)), dim3(512), 0, stream,
                     att_bf, wprojT, (void*)out, b_proj, Mtok, Cc, Cc, Cc / 256);
}

// Round 12
// 243.154 us; speedup vs baseline: 1.4395x; 1.0125x over previous
//
#include <hip/hip_runtime.h>
#include <hip/hip_bf16.h>
#include <stdint.h>

typedef __attribute__((ext_vector_type(8))) short short8;
typedef __attribute__((ext_vector_type(4))) float floatx4;

#define DEVINL static __device__ __forceinline__

DEVINL float bfu(short v) {
  union { uint32_t i; float f; } x; x.i = ((uint32_t)(uint16_t)v) << 16; return x.f;
}
DEVINL uint16_t f2bf(float f) {
  union { float f; uint32_t i; } x; x.f = f;
  uint32_t i = x.i;
  i += 0x7fff + ((i >> 16) & 1);   // RNE
  return (uint16_t)(i >> 16);
}

// ============ fused prep: fp32->bf16 cvt of x + both weight transposes ============
DEVINL void transpose_tile(const float* in, uint16_t* out, int K, int N,
                           int bx, int by, float (*tile)[65]) {
  const int tn = bx * 64;
  const int tk = by * 64;
  const int tx = threadIdx.x & 63;
  const int ty = threadIdx.x >> 6;   // 0..3
#pragma unroll
  for (int i = 0; i < 64; i += 4)
    tile[ty + i][tx] = in[(long)(tk + ty + i) * N + tn + tx];
  __syncthreads();
#pragma unroll
  for (int i = 0; i < 64; i += 4)
    out[(long)(tn + ty + i) * K + tk + tx] = f2bf(tile[tx][ty + i]);
}

__global__ __launch_bounds__(256)
void k_prep(const float* __restrict__ x, uint16_t* __restrict__ x_bf, int n4,
            const float* __restrict__ w_qkv, uint16_t* __restrict__ wqkvT,
            const float* __restrict__ w_proj, uint16_t* __restrict__ wprojT) {
  __shared__ float tile[64][65];
  const int bid = blockIdx.x;
  if (bid < 2048) {
    int i = bid * 256 + threadIdx.x;
    const int stride = 2048 * 256;
    for (; i < n4; i += stride) {
      float4 v = ((const float4*)x)[i];
      ushort4 o;
      o.x = f2bf(v.x); o.y = f2bf(v.y); o.z = f2bf(v.z); o.w = f2bf(v.w);
      ((ushort4*)x_bf)[i] = o;
    }
  } else if (bid < 2048 + 36 * 12) {
    const int tq = bid - 2048;
    transpose_tile(w_qkv, wqkvT, 768, 2304, tq % 36, tq / 36, tile);
  } else {
    const int tp = bid - (2048 + 36 * 12);
    transpose_tile(w_proj, wprojT, 768, 768, tp % 12, tp / 12, tile);
  }
}

// ============ 128x128 bf16 GEMM, C = A @ B^T (B stored [N][K]) ============
// R12: 1:1 shrink of the R7-verified 256^2 kernel to 128^2 / 256 threads /
// 64 KB LDS => 2 blocks/CU. LEDGER IDENTICAL to R7 (same counts):
//   prologue: t0 full [B_lo,B_hi,A_lo,A_hi]=8 + B_lo(t1),A_lo(t1)=4 ; vmcnt(4)
//   loop kt:  16 ds_reads (a:8, bv0:4, bv1:4) ;
//             early stage B_hi(t1),A_hi(t1)->nbuf (4) ;
//             lgkm(4) [c1 needs first 12 reads] ; MFMA c1 (16: a x bv0) ;
//             lgkm(0) ; BARRIER ;
//             mid stage B_lo(t2),A_lo(t2)->cbuf (4) ; MFMA c2 (16: a x bv1) ;
//             vmcnt(4) [queue 12, oldest 8 = tile t1 complete] ; BARRIER.
// Halves are 64 rows (8 KB). Waves: 2M x 2N, wave tile 64x64, acc[4][4].
// T2 swizzle (row&7)<<4 both-sides; T5 setprio; XCD-bijective remap (m204).
template<int OUT_BF16>
__global__ __launch_bounds__(256, 2)
void k_gemm128(const uint16_t* __restrict__ A,   // [M][Kd] bf16
               const uint16_t* __restrict__ B,   // [N][Kd] bf16
               void* __restrict__ Cout,          // bf16 [M][N] or fp32 [M][N]
               const float* __restrict__ bias,   // nullable (fp32 path)
               int M, int N, int Kd, int tilesN)
{
  __shared__ uint16_t As[2][2][4096];  // [buf][half(64 rows)][64 x 64]
  __shared__ uint16_t Bs[2][2][4096];

  const int nwg = gridDim.x;
  const int orig = blockIdx.x;
  const int q = nwg >> 3, r = nwg & 7;
  const int xcd = orig & 7, seq = orig >> 3;
  const int wgid = (xcd < r ? xcd * (q + 1) : r * (q + 1) + (xcd - r) * q) + seq;
  const int mt = wgid / tilesN;
  const int nt = wgid - mt * tilesN;

  const int t = threadIdx.x;           // 0..255
  const int l = t & 63;
  const int w = t >> 6;                // 0..3
  const int wm = w >> 1;               // 0..1
  const int wn = w & 1;                // 0..1
  const long m0 = (long)mt * 128;
  const long n0 = (long)nt * 128;

  // staging: thread covers rows (t>>3) and (t>>3)+32 of a 64-row half.
  // Source col pre-swizzled so LDS[row][c] = G[row][c ^ ((row&7)<<4 bytes)];
  // row%8 within chunk = (t>>3)&7 = l>>3, same as the verified kernel.
  const int srow0 = t >> 3;            // 0..31
  const int scol  = ((l & 7) ^ (l >> 3)) * 8;
  const int wbyte = w * 1024;

  const uint16_t* Abase = A + m0 * Kd;
  const uint16_t* Bbase = B + n0 * Kd;

  const int fr = l & 15;
  const int kg = l >> 4;
  const int xorv = (l & 7) << 4;
  const int cb0 = (kg * 16) ^ xorv;
  const int cb1 = (64 + kg * 16) ^ xorv;

  floatx4 acc[4][4];
#pragma unroll
  for (int m = 0; m < 4; ++m)
#pragma unroll
    for (int n = 0; n < 4; ++n)
      acc[m][n] = (floatx4){0.f, 0.f, 0.f, 0.f};

  const int nK = Kd >> 6;   // 12 (even)

  // stage one 64-row half: 2 gload_lds (rows srow0, srow0+32)
  auto stage = [&](uint16_t* ldsHalf, const uint16_t* gHalf, int ktile) {
    const uint16_t* g0 = gHalf + (long)srow0 * Kd + ktile * 64 + scol;
    __builtin_amdgcn_global_load_lds(
        (const __attribute__((address_space(1))) void*)g0,
        (__attribute__((address_space(3))) void*)((char*)ldsHalf + wbyte), 16, 0, 0);
    __builtin_amdgcn_global_load_lds(
        (const __attribute__((address_space(1))) void*)(g0 + (long)32 * Kd),
        (__attribute__((address_space(3))) void*)((char*)ldsHalf + 4096 + wbyte), 16, 0, 0);
  };
  // wave's A rows = wm*64 + mm*16 + fr  -> half wm, byte (mm*16+fr)*128
  auto rdA = [&](int buf, int mm, int kk) -> short8 {
    const char* p = (const char*)&As[buf][wm][0] + mm * 2048 + fr * 128 + (kk ? cb1 : cb0);
    return *(const short8*)p;
  };
  auto rdB = [&](int buf, int nn, int kk) -> short8 {
    const char* p = (const char*)&Bs[buf][wn][0] + nn * 2048 + fr * 128 + (kk ? cb1 : cb0);
    return *(const short8*)p;
  };

  // ---- prologue: t0 full (8 loads) + B_lo(t1),A_lo(t1) (4); vmcnt(4) ----
  stage(&Bs[0][0][0], Bbase, 0);
  stage(&Bs[0][1][0], Bbase + (long)64 * Kd, 0);
  stage(&As[0][0][0], Abase, 0);
  stage(&As[0][1][0], Abase + (long)64 * Kd, 0);
  {
    int t1 = 1 % nK;
    stage(&Bs[t1 & 1][0][0], Bbase, t1);
    stage(&As[t1 & 1][0][0], Abase, t1);
  }
  asm volatile("s_waitcnt vmcnt(4)" ::: "memory");
  __builtin_amdgcn_s_barrier();

  short8 a[4][2], bv0[2][2], bv1[2][2];

  for (int kt = 0; kt < nK; ++kt) {
    const int cbuf = kt & 1;
    const int nbuf = cbuf ^ 1;
    const int t1 = (kt + 1) % nK;
    const int t2 = (kt + 2) % nK;

    // 16 cbuf ds_reads: a (8), bv0 (4), bv1 (4) — reads first (R9 lesson)
#pragma unroll
    for (int mm = 0; mm < 4; ++mm) { a[mm][0] = rdA(cbuf, mm, 0); a[mm][1] = rdA(cbuf, mm, 1); }
#pragma unroll
    for (int nn = 0; nn < 2; ++nn) { bv0[nn][0] = rdB(cbuf, nn, 0); bv0[nn][1] = rdB(cbuf, nn, 1); }
#pragma unroll
    for (int nn = 0; nn < 2; ++nn) { bv1[nn][0] = rdB(cbuf, 2 + nn, 0); bv1[nn][1] = rdB(cbuf, 2 + nn, 1); }

    // early 2-deep stage: t1 upper halves -> nbuf (never read this K-tile)
    stage(&Bs[nbuf][1][0], Bbase + (long)64 * Kd, t1);
    stage(&As[nbuf][1][0], Abase + (long)64 * Kd, t1);

    asm volatile("s_waitcnt lgkmcnt(4)" ::: "memory");   // first 12 reads (a+bv0) done
    __builtin_amdgcn_s_setprio(1);
#pragma unroll
    for (int mm = 0; mm < 4; ++mm)
#pragma unroll
      for (int nn = 0; nn < 2; ++nn) {
        acc[mm][nn] = __builtin_amdgcn_mfma_f32_16x16x32_bf16(a[mm][0], bv0[nn][0], acc[mm][nn], 0, 0, 0);
        acc[mm][nn] = __builtin_amdgcn_mfma_f32_16x16x32_bf16(a[mm][1], bv0[nn][1], acc[mm][nn], 0, 0, 0);
      }
    asm volatile("s_waitcnt lgkmcnt(0)" ::: "memory");
    __builtin_amdgcn_s_barrier();   // all waves done reading cbuf

    // mid stage: t2 lower halves -> cbuf; overlaps MFMA c2
    stage(&Bs[cbuf][0][0], Bbase, t2);
    stage(&As[cbuf][0][0], Abase, t2);
#pragma unroll
    for (int mm = 0; mm < 4; ++mm)
#pragma unroll
      for (int nn = 0; nn < 2; ++nn) {
        acc[mm][2 + nn] = __builtin_amdgcn_mfma_f32_16x16x32_bf16(a[mm][0], bv1[nn][0], acc[mm][2 + nn], 0, 0, 0);
        acc[mm][2 + nn] = __builtin_amdgcn_mfma_f32_16x16x32_bf16(a[mm][1], bv1[nn][1], acc[mm][2 + nn], 0, 0, 0);
      }
    __builtin_amdgcn_s_setprio(0);

    // gate: queue = [B_lo,A_lo(t1) | B_hi,A_hi(t1) | B_lo,A_lo(t2)] = 12;
    // oldest 8 = tile t1 fully resident => vmcnt(4)
    asm volatile("s_waitcnt vmcnt(4)" ::: "memory");
    __builtin_amdgcn_s_barrier();
  }

  // drain wrapped tail stages (they write As/Bs)
  asm volatile("s_waitcnt vmcnt(0)" ::: "memory");
  __builtin_amdgcn_s_barrier();

  // C/D frag layout: col = lane&15, row = (lane>>4)*4 + reg
  const int orow = (l >> 4) * 4;
  const int ocol = l & 15;
  if (OUT_BF16) {
    uint16_t* C = (uint16_t*)Cout;
    char* eb = (char*)&As[0][0][0] + (size_t)w * 4096;   // wave-private 4KB
    const int rr0 = l >> 3;
    const int cc0 = (l & 7) * 8;
#pragma unroll
    for (int mm = 0; mm < 4; ++mm) {
#pragma unroll
      for (int nn = 0; nn < 4; ++nn)
#pragma unroll
        for (int r2 = 0; r2 < 4; ++r2) {
          int rrow = orow + r2;
          int byo = ((rrow * 64 + nn * 16 + ocol) * 2) ^ ((rrow & 7) << 4);
          *(uint16_t*)(eb + byo) = f2bf(acc[mm][nn][r2]);
        }
#pragma unroll
      for (int p = 0; p < 2; ++p) {
        int rrow = rr0 + p * 8;
        int byo = ((rrow * 64 + cc0) * 2) ^ ((rrow & 7) << 4);
        short8 vvv = *(const short8*)(eb + byo);
        *(short8*)(&C[(m0 + wm * 64 + mm * 16 + rrow) * N + n0 + wn * 64 + cc0]) = vvv;
      }
    }
  } else {
    float* C = (float*)Cout;
    float* eb = (float*)&As[0][0][0] + (size_t)w * 1024;  // wave-private 4KB
    const int rr0 = l >> 4;
    const int cc0 = (l & 15) * 4;
    float4 bias4 = make_float4(0.f, 0.f, 0.f, 0.f);
    if (bias) bias4 = *(const float4*)(bias + n0 + wn * 64 + cc0);
#pragma unroll
    for (int mm = 0; mm < 4; ++mm) {
#pragma unroll
      for (int nn = 0; nn < 4; ++nn)
#pragma unroll
        for (int r2 = 0; r2 < 4; ++r2)
          eb[(orow + r2) * 64 + nn * 16 + ocol] = acc[mm][nn][r2];
#pragma unroll
      for (int p = 0; p < 4; ++p) {
        int rrow = rr0 + p * 4;
        float4 vvv = *(const float4*)(eb + rrow * 64 + cc0);
        vvv.x += bias4.x; vvv.y += bias4.y; vvv.z += bias4.z; vvv.w += bias4.w;
        *(float4*)(&C[(m0 + wm * 64 + mm * 16 + rrow) * N + n0 + wn * 64 + cc0]) = vvv;
      }
    }
  }
}

// ---------------- per-token 6-head attention, 16 lanes per token ----------------
__global__ __launch_bounds__(256)
void k_attn(const uint16_t* __restrict__ qkv, uint16_t* __restrict__ outp) {
  const int wid = blockIdx.x * 4 + (threadIdx.x >> 6);
  const int l = threadIdx.x & 63;
  const int sub = l >> 4;
  const int i = l & 15;
  const int token = wid * 4 + sub;
  const uint16_t* row = qkv + (long)token * 2304 + i * 8;

  short8 kv[6];
  float qf[6][8];
#pragma unroll
  for (int h = 0; h < 6; ++h) {
    short8 qv = *(const short8*)(row + h * 128);
    kv[h] = *(const short8*)(row + 768 + h * 128);
#pragma unroll
    for (int e = 0; e < 8; ++e) qf[h][e] = bfu(qv[e]);
  }

  float s[36];
#pragma unroll
  for (int g = 0; g < 6; ++g) {
    float kf[8];
#pragma unroll
    for (int e = 0; e < 8; ++e) kf[e] = bfu(kv[g][e]);
#pragma unroll
    for (int h = 0; h < 6; ++h) {
      float a = 0.f;
#pragma unroll
      for (int e = 0; e < 8; ++e) a += qf[h][e] * kf[e];
      s[h * 6 + g] = a;
    }
  }

#pragma unroll
  for (int off = 8; off > 0; off >>= 1)
#pragma unroll
    for (int j = 0; j < 36; ++j)
      s[j] += __shfl_xor(s[j], off, 64);

  const float scale = 0.088388347648318447f;  // 128^-0.5
  float p[36];
#pragma unroll
  for (int h = 0; h < 6; ++h) {
    float mx = s[h * 6];
#pragma unroll
    for (int g = 1; g < 6; ++g) mx = fmaxf(mx, s[h * 6 + g]);
    float sum = 0.f;
#pragma unroll
    for (int g = 0; g < 6; ++g) {
      float e = __expf((s[h * 6 + g] - mx) * scale);
      p[h * 6 + g] = e; sum += e;
    }
    float inv = 1.f / sum;
#pragma unroll
    for (int g = 0; g < 6; ++g) p[h * 6 + g] *= inv;
  }

  float o[6][8];
#pragma unroll
  for (int h = 0; h < 6; ++h)
#pragma unroll
    for (int e = 0; e < 8; ++e) o[h][e] = 0.f;
#pragma unroll
  for (int g = 0; g < 6; ++g) {
    short8 vv = *(const short8*)(row + 1536 + g * 128);
    float vf[8];
#pragma unroll
    for (int e = 0; e < 8; ++e) vf[e] = bfu(vv[e]);
#pragma unroll
    for (int h = 0; h < 6; ++h)
#pragma unroll
      for (int e = 0; e < 8; ++e) o[h][e] += p[h * 6 + g] * vf[e];
  }

  const int b = token >> 12, nn = token & 4095;
#pragma unroll
  for (int h = 0; h < 6; ++h) {
    short8 ov;
#pragma unroll
    for (int e = 0; e < 8; ++e) ov[e] = (short)f2bf(o[h][e]);
    *(short8*)(outp + ((long)(b * 6 + h) * 4096 + nn) * 128 + i * 8) = ov;
  }
}

extern "C" void kernel_launch(void* const* d_in, const int* in_sizes, int n_in,
                              void* d_out, int out_size, void* d_ws, size_t ws_size,
                              hipStream_t stream) {
  const float* x      = (const float*)d_in[0];
  const float* w_qkv  = (const float*)d_in[1];
  const float* w_proj = (const float*)d_in[2];
  const float* b_proj = (const float*)d_in[3];
  float* out = (float*)d_out;

  const int Cc = 768, C3 = 2304;
  const int Mtok = in_sizes[0] / Cc;  // 32768

  char* ws = (char*)d_ws;
  uint16_t* x_bf   = (uint16_t*)ws;                            // 50,331,648 B
  uint16_t* att_bf = x_bf;                                     // reuse (x_bf dead after GEMM1)
  uint16_t* qkv_bf = (uint16_t*)(ws + 50331648);               // 150,994,944 B
  uint16_t* wqkvT  = (uint16_t*)(ws + 50331648 + 150994944);   // 3,538,944 B
  uint16_t* wprojT = (uint16_t*)(ws + 50331648 + 150994944 + 3538944); // 1,179,648 B

  hipLaunchKernelGGL(k_prep, dim3(2048 + 432 + 144), dim3(256), 0, stream,
                     x, x_bf, Mtok * Cc / 4, w_qkv, wqkvT, w_proj, wprojT);

  // GEMM1: 256 x 18 = 4608 blocks = 9.0 exact rounds at 2 blocks/CU
  hipLaunchKernelGGL((k_gemm128<1>), dim3((Mtok / 128) * (C3 / 128)), dim3(256), 0, stream,
                     x_bf, wqkvT, (void*)qkv_bf, (const float*)nullptr, Mtok, C3, Cc, C3 / 128);

  hipLaunchKernelGGL(k_attn, dim3(Mtok / 16), dim3(256), 0, stream, qkv_bf, att_bf);

  // GEMM2: 256 x 6 = 1536 blocks = 3.0 exact rounds at 2 blocks/CU
  hipLaunchKernelGGL((k_gemm128<0>), dim3((Mtok / 128) * (Cc / 128)), dim3(256), 0, stream,
                     att_bf, wprojT, (void*)out, b_proj, Mtok, Cc, Cc, Cc / 128);
}